// Round 8
// baseline (107.313 us; speedup 1.0000x reference)
//
#include <hip/hip_runtime.h>
#include <hip/hip_bf16.h>

using bf16x8 = __attribute__((ext_vector_type(8))) short;
using f32x4  = __attribute__((ext_vector_type(4))) float;

static __device__ __forceinline__ short f2bf(float f) {
  union { float f; unsigned u; } x; x.f = f;
  unsigned r = x.u + 0x7fffu + ((x.u >> 16) & 1u);
  return (short)(r >> 16);
}
static __device__ __forceinline__ float bf2f(short b) {
  union { unsigned u; float f; } x; x.u = ((unsigned)(unsigned short)b) << 16;
  return x.f;
}
static __device__ __forceinline__ unsigned pack_bf2(float lo, float hi) {
  __hip_bfloat162 h = __float22bfloat162_rn(float2{lo, hi});   // v_cvt_pk_bf16_f32
  unsigned u; __builtin_memcpy(&u, &h, 4); return u;
}
static __device__ __forceinline__ float exp2_raw(float x) {
  float r; asm("v_exp_f32 %0, %1" : "=v"(r) : "v"(x)); return r;  // 1 inst, no libm fixups
}
static __device__ __forceinline__ void gll16(const void* g, void* l) {
  __builtin_amdgcn_global_load_lds((__attribute__((address_space(1))) const void*)g,
                                   (__attribute__((address_space(3))) void*)l, 16, 0, 0);
}

// ---------------- mask -> bit-packed u64 per (row, 64-key tile) ----------------
__global__ void k_pack_mask(const unsigned* __restrict__ src_u32,
                            unsigned long long* __restrict__ out, int n) {
  unsigned probe = src_u32[threadIdx.x & 63];
  const bool u8mode = (__ballot(probe > 1u) != 0ull);   // block-uniform
  const unsigned char* s8 = (const unsigned char*)src_u32;
  const int* s32 = (const int*)src_u32;
  for (int e = blockIdx.x * blockDim.x + threadIdx.x; e < n; e += gridDim.x * blockDim.x) {
    int v = u8mode ? (int)s8[e] : s32[e];
    unsigned long long b = __ballot(v != 0);
    if ((threadIdx.x & 63) == 0) out[e >> 6] = b;
  }
}

// ---------------- f32 -> bf16 (two tensors, y-fused) ----------------
__global__ void k_cvt_bf16(const float* __restrict__ in0, short* __restrict__ out0,
                           const float* __restrict__ in1, short* __restrict__ out1, int n4) {
  const float* in = blockIdx.y ? in1 : in0;
  short* out = blockIdx.y ? out1 : out0;
  for (int i = blockIdx.x * blockDim.x + threadIdx.x; i < n4; i += gridDim.x * blockDim.x) {
    float4 v = reinterpret_cast<const float4*>(in)[i];
    short4 o;
    o.x = f2bf(v.x); o.y = f2bf(v.y); o.z = f2bf(v.z); o.w = f2bf(v.w);
    reinterpret_cast<short4*>(out)[i] = o;
  }
}

// transpose 1024x1024 f32 W[k][n] -> bf16 Wt[n][k]; z selects one of 3 weights
__global__ void k_transpose_cvt(const float* __restrict__ W0, const float* __restrict__ W1,
                                const float* __restrict__ W2, short* __restrict__ out3) {
  __shared__ float tile[32][33];
  const float* in = blockIdx.z == 0 ? W0 : (blockIdx.z == 1 ? W1 : W2);
  short* out = out3 + (size_t)blockIdx.z * 1024 * 1024;
  int x = blockIdx.x * 32 + threadIdx.x;
  int y0 = blockIdx.y * 32;
  for (int j = 0; j < 32; j += 8)
    tile[threadIdx.y + j][threadIdx.x] = in[(size_t)(y0 + threadIdx.y + j) * 1024 + x];
  __syncthreads();
  int xo = blockIdx.y * 32 + threadIdx.x;
  int yo = blockIdx.x * 32;
  for (int j = 0; j < 32; j += 8)
    out[(size_t)(yo + threadIdx.y + j) * 1024 + xo] = f2bf(tile[threadIdx.x][threadIdx.y + j]);
}

// transpose bf16 Qp[b, s, h*64+d] -> Vtg[(b*16+h)*64+d][s]  (per-head V^T)
__global__ void k_vt_transpose(const short* __restrict__ Qp, short* __restrict__ Vtg) {
  __shared__ short T[64 * 64];
  const int st = blockIdx.x, h = blockIdx.y, b = blockIdx.z;
  const int tid = threadIdx.x;
#pragma unroll
  for (int c = 0; c < 2; ++c) {
    int ch = c * 256 + tid;
    int row = ch >> 3, cn = ch & 7;
    bf16x8 v = *reinterpret_cast<const bf16x8*>(
        &Qp[(size_t)(b * 1024 + st * 64 + row) * 1024 + h * 64 + cn * 8]);
    *reinterpret_cast<bf16x8*>(&T[row * 64 + ((cn ^ (row & 7)) * 8)]) = v;
  }
  __syncthreads();
#pragma unroll
  for (int c = 0; c < 2; ++c) {
    int ch = c * 256 + tid;
    int d = ch >> 3, sc = ch & 7;
    bf16x8 v;
#pragma unroll
    for (int j = 0; j < 8; ++j) {
      int s_loc = sc * 8 + j;
      v[j] = T[s_loc * 64 + (((d >> 3) ^ j) * 8) + (d & 7)];
    }
    *reinterpret_cast<bf16x8*>(
        &Vtg[(size_t)((b * 16 + h) * 64 + d) * 1024 + st * 64 + sc * 8]) = v;
  }
}

// ---------------- bf16 MFMA GEMM body: C = A @ Bt^T + bias ----------------
// 128x128 tile, 4 waves (2x2, 64x64/wave, 4x4 frags), BK=64, 2-buffer,
// early-issue stage -> compute -> vmcnt(0)+barrier. Conflict-free chunk^row swizzle.
template<int OUT_BF16, int M, int N, int K>
__device__ __forceinline__ void gemm_body(const short* __restrict__ A,
                                          const short* __restrict__ Bt,
                                          const float* __restrict__ bias,
                                          void* __restrict__ C) {
  __shared__ short Al[2][128 * 64];
  __shared__ short Bl[2][128 * 64];
  const int tid  = threadIdx.x;
  const int lane = tid & 63, wid = tid >> 6;
  const int g = lane >> 4, lr = lane & 15;
  const int wm = wid >> 1, wn = wid & 1;
  constexpr int nbx = N >> 7;
  constexpr int nwg = nbx * (M >> 7);
  const int lin = blockIdx.y * nbx + blockIdx.x;
  const int orig = (lin & 7) * (nwg >> 3) + (lin >> 3);   // XCD swizzle (nwg % 8 == 0)
  const int m0 = (orig / nbx) * 128, n0 = (orig % nbx) * 128;
  const int srow = lane >> 3;
  const int sch  = ((lane & 7) ^ srow) * 8;     // source chunk swizzle (row&7 == srow)

  f32x4 acc[4][4];
#pragma unroll
  for (int i = 0; i < 4; ++i)
#pragma unroll
    for (int j = 0; j < 4; ++j) acc[i][j] = (f32x4){0.f, 0.f, 0.f, 0.f};

  constexpr int NT = K >> 6;
  auto stage = [&](int buf, int kt) {
#pragma unroll
    for (int s = 0; s < 4; ++s)
      gll16(&A[(size_t)(m0 + s * 32 + wid * 8 + srow) * K + kt + sch],
            &Al[buf][(s * 32 + wid * 8) * 64]);
#pragma unroll
    for (int s = 0; s < 4; ++s)
      gll16(&Bt[(size_t)(n0 + s * 32 + wid * 8 + srow) * K + kt + sch],
            &Bl[buf][(s * 32 + wid * 8) * 64]);
  };

  stage(0, 0);
  asm volatile("s_waitcnt vmcnt(0)" ::: "memory");
  __builtin_amdgcn_s_barrier();
  asm volatile("" ::: "memory");

#pragma unroll 1
  for (int t = 0; t < NT; ++t) {
    const int cur = t & 1;
    if (t + 1 < NT) stage(cur ^ 1, (t + 1) * 64);   // readers of that buf done last iter
#pragma unroll
    for (int kb = 0; kb < 2; ++kb) {
      const int cs = ((kb * 4 + g) ^ (lr & 7)) * 8;      // swizzled read chunk
      bf16x8 af[4], bfr[4];
#pragma unroll
      for (int i = 0; i < 4; ++i)
        af[i] = *reinterpret_cast<const bf16x8*>(&Al[cur][(wm * 64 + i * 16 + lr) * 64 + cs]);
#pragma unroll
      for (int j = 0; j < 4; ++j)
        bfr[j] = *reinterpret_cast<const bf16x8*>(&Bl[cur][(wn * 64 + j * 16 + lr) * 64 + cs]);
#pragma unroll
      for (int i = 0; i < 4; ++i)
#pragma unroll
        for (int j = 0; j < 4; ++j)
          acc[i][j] = __builtin_amdgcn_mfma_f32_16x16x32_bf16(af[i], bfr[j], acc[i][j], 0, 0, 0);
    }
    if (t + 1 < NT) {
      asm volatile("s_waitcnt vmcnt(0)" ::: "memory");  // stage(t+1) complete (had full flight)
      __builtin_amdgcn_s_barrier();                     // + everyone done reading cur
      asm volatile("" ::: "memory");
    }
  }

#pragma unroll
  for (int i = 0; i < 4; ++i) {
    int row = m0 + wm * 64 + i * 16 + g * 4;
#pragma unroll
    for (int j = 0; j < 4; ++j) {
      int col = n0 + wn * 64 + j * 16 + lr;
      float bv = bias[col];
#pragma unroll
      for (int r = 0; r < 4; ++r) {
        float v = acc[i][j][r] + bv;
        if (OUT_BF16) ((short*)C)[(size_t)(row + r) * N + col] = f2bf(v);
        else          ((float*)C)[(size_t)(row + r) * N + col] = v;
      }
    }
  }
}

// z=0: Q projection, z=1: K projection
__launch_bounds__(256)
__global__ void k_gemm_qk(const short* __restrict__ A0, const short* __restrict__ A1,
                          const short* __restrict__ Bt3,
                          const float* __restrict__ b0, const float* __restrict__ b1,
                          short* __restrict__ C0, short* __restrict__ C1) {
  if (blockIdx.z == 0) gemm_body<1, 4096, 1024, 1024>(A0, Bt3,               b0, C0);
  else                 gemm_body<1, 4096, 1024, 1024>(A1, Bt3 + 1024 * 1024, b1, C1);
}

__launch_bounds__(256)
__global__ void k_gemm_out(const short* __restrict__ A, const short* __restrict__ Bt,
                           const float* __restrict__ bias, float* __restrict__ C) {
  gemm_body<0, 4096, 1024, 1024>(A, Bt, bias, C);
}

// ---------------- fused masked attention, swapped-operand flash ----------------
// (byte-identical to R7 — isolate the GEMM change)
__launch_bounds__(512)
__global__ void k_attention(const short* __restrict__ Qp, const short* __restrict__ Kp,
                            const short* __restrict__ Vtg,
                            const unsigned long long* __restrict__ mb,
                            short* __restrict__ O) {
  __shared__ short Kl[3][64 * 64];   // [key][d], chunk-swizzled linear
  __shared__ short Vl[3][64 * 64];   // [d][key], chunk-swizzled linear
  __shared__ short Pl[8][16 * 72];   // per-wave P[q][key] (also output staging)
  const int tid  = threadIdx.x;
  const int lane = tid & 63, wid = tid >> 6;
  const int g = lane >> 4, lr = lane & 15;
  const int g4 = 4 * g;
  const int bid = (blockIdx.x & 7) * 64 + (blockIdx.x >> 3);  // XCD swizzle
  const int qt = bid & 7, h = (bid >> 3) & 15, b = bid >> 7;
  const int qb = qt * 128 + wid * 16;
  const int srow = lane >> 3;
  const int sch  = ((lane & 7) ^ srow) * 8;

  const size_t qrow = (size_t)(b * 1024 + qb + lr);
  const float qs = 0.125f * 1.44269504088896340736f;
  bf16x8 aq[2];
#pragma unroll
  for (int db = 0; db < 2; ++db) {
    bf16x8 raw = *reinterpret_cast<const bf16x8*>(&Qp[qrow * 1024 + h * 64 + db * 32 + g * 8]);
#pragma unroll
    for (int j = 0; j < 8; j += 2) {
      unsigned pk = pack_bf2(bf2f(raw[j]) * qs, bf2f(raw[j + 1]) * qs);
      aq[db][j]     = (short)(pk & 0xffffu);
      aq[db][j + 1] = (short)(pk >> 16);
    }
  }

  const unsigned long long* mrow = &mb[qrow * 16];
  const short* Ksrc = &Kp[(size_t)(b * 1024 + wid * 8 + srow) * 1024 + h * 64 + sch];
  const short* Vsrc = &Vtg[(size_t)((b * 16 + h) * 64 + wid * 8 + srow) * 1024 + sch];

  f32x4 o[4];
#pragma unroll
  for (int d = 0; d < 4; ++d) o[d] = (f32x4){0.f, 0.f, 0.f, 0.f};
  float l_part = 0.f;
  short* Pw = &Pl[wid][lr * 72 + g4];

  gll16(Ksrc,                     &Kl[0][(wid * 8) * 64]);
  gll16(Vsrc,                     &Vl[0][(wid * 8) * 64]);
  gll16(Ksrc + (size_t)64 * 1024, &Kl[1][(wid * 8) * 64]);
  gll16(Vsrc + 64,                &Vl[1][(wid * 8) * 64]);
  unsigned long long mwA = mrow[0];
  unsigned long long mwB = mrow[1];
  unsigned long long mwC = 0;
  const float keep = (mwA & 1ull) ? 0.f : 1.f;   // redundant row-keep, ~mask[b,q,0]

  int cur = 0;   // kt % 3
  int b2  = 2;   // (kt+2) % 3 == (kt-1) % 3
#pragma unroll 1
  for (int kt = 0; kt < 16; ++kt) {
    if (kt >= 1) {
      const short* Vb = Vl[b2];
      __builtin_amdgcn_s_setprio(1);
#pragma unroll
      for (int kb = 0; kb < 2; ++kb) {
        bf16x8 pa = *reinterpret_cast<const bf16x8*>(&Pl[wid][lr * 72 + kb * 32 + g * 8]);
        const int cs = ((kb * 4 + g) ^ (lr & 7)) * 8;
#pragma unroll
        for (int d = 0; d < 4; ++d) {
          bf16x8 vf = *reinterpret_cast<const bf16x8*>(&Vb[(d * 16 + lr) * 64 + cs]);
          o[d] = __builtin_amdgcn_mfma_f32_16x16x32_bf16(vf, pa, o[d], 0, 0, 0);
        }
      }
      __builtin_amdgcn_s_setprio(0);
    }

    if (kt < 15) asm volatile("s_waitcnt vmcnt(4)" ::: "memory");  // stage(kt) drained
    else         asm volatile("s_waitcnt vmcnt(0)" ::: "memory");
    __builtin_amdgcn_s_barrier();
    asm volatile("" ::: "memory");

    if (kt + 2 < 16) {
      gll16(Ksrc + (size_t)(kt + 2) * 64 * 1024, &Kl[b2][(wid * 8) * 64]);
      gll16(Vsrc + (kt + 2) * 64,                &Vl[b2][(wid * 8) * 64]);
      mwC = mrow[kt + 2];                        // consumed 2 iters later
    }

    const unsigned mlo = (unsigned)mwA;
    const unsigned mhi = (unsigned)(mwA >> 32);

#pragma unroll
    for (int kc = 0; kc < 4; ++kc) {
      f32x4 a = (f32x4){0.f, 0.f, 0.f, 0.f};
      __builtin_amdgcn_s_setprio(1);
#pragma unroll
      for (int db = 0; db < 2; ++db) {
        bf16x8 kf = *reinterpret_cast<const bf16x8*>(
            &Kl[cur][(kc * 16 + lr) * 64 + (((db * 4 + g) ^ (lr & 7)) * 8)]);
        a = __builtin_amdgcn_mfma_f32_16x16x32_bf16(kf, aq[db], a, 0, 0, 0);
      }
      __builtin_amdgcn_s_setprio(0);
      const unsigned wk = ((kc < 2 ? mlo : mhi) >> (((kc & 1) << 4) + g4)) & 0xFu;
      float p0 = (wk & 1u) ? 0.f : exp2_raw(a[0]);
      float p1 = (wk & 2u) ? 0.f : exp2_raw(a[1]);
      float p2 = (wk & 4u) ? 0.f : exp2_raw(a[2]);
      float p3 = (wk & 8u) ? 0.f : exp2_raw(a[3]);
      l_part += (p0 + p1) + (p2 + p3);
      unsigned lo = pack_bf2(p0, p1), hi = pack_bf2(p2, p3);
      unsigned long long w = (unsigned long long)lo | ((unsigned long long)hi << 32);
      *reinterpret_cast<unsigned long long*>(&Pw[kc * 16]) = w;   // one ds_write_b64
    }
    mwA = mwB; mwB = mwC;
    cur = (cur == 2) ? 0 : cur + 1;
    b2  = (b2  == 2) ? 0 : b2  + 1;
    asm volatile("" ::: "memory");
  }

  {
    const short* Vb = Vl[0];
    __builtin_amdgcn_s_setprio(1);
#pragma unroll
    for (int kb = 0; kb < 2; ++kb) {
      bf16x8 pa = *reinterpret_cast<const bf16x8*>(&Pl[wid][lr * 72 + kb * 32 + g * 8]);
      const int cs = ((kb * 4 + g) ^ (lr & 7)) * 8;
#pragma unroll
      for (int d = 0; d < 4; ++d) {
        bf16x8 vf = *reinterpret_cast<const bf16x8*>(&Vb[(d * 16 + lr) * 64 + cs]);
        o[d] = __builtin_amdgcn_mfma_f32_16x16x32_bf16(vf, pa, o[d], 0, 0, 0);
      }
    }
    __builtin_amdgcn_s_setprio(0);
  }

  float l_run = l_part;
  l_run += __shfl_xor(l_run, 16);
  l_run += __shfl_xor(l_run, 32);

  const float inv = (l_run > 0.f) ? keep / l_run : 0.f;
  {
    short* Ow = &Pl[wid][lr * 72 + g4];
#pragma unroll
    for (int d = 0; d < 4; ++d)
#pragma unroll
      for (int hh = 0; hh < 2; ++hh)
        *reinterpret_cast<unsigned*>(&Ow[d * 16 + 2 * hh]) =
            pack_bf2(o[d][2 * hh] * inv, o[d][2 * hh + 1] * inv);
  }
#pragma unroll
  for (int it = 0; it < 2; ++it) {
    int qq = it * 8 + srow;
    bf16x8 val = *reinterpret_cast<const bf16x8*>(&Pl[wid][qq * 72 + (lane & 7) * 8]);
    *reinterpret_cast<bf16x8*>(
        &O[(size_t)(b * 1024 + qt * 128 + wid * 16 + qq) * 1024 + h * 64 + (lane & 7) * 8]) = val;
  }
}

extern "C" void kernel_launch(void* const* d_in, const int* in_sizes, int n_in,
                              void* d_out, int out_size, void* d_ws, size_t ws_size,
                              hipStream_t stream) {
  const float* query  = (const float*)d_in[0];
  const float* key_in = (const float*)d_in[1];
  const void*  mask_raw = d_in[2];
  const float* Wq = (const float*)d_in[3];
  const float* bq = (const float*)d_in[4];
  const float* Wk = (const float*)d_in[5];
  const float* bk = (const float*)d_in[6];
  const float* Wp = (const float*)d_in[7];
  const float* bp = (const float*)d_in[8];

  char* ws = (char*)d_ws;
  size_t off = 0;
  auto alloc = [&](size_t bytes) {
    char* p = ws + off;
    off = (off + bytes + 255) & ~(size_t)255;
    return p;
  };
  unsigned long long* packb = (unsigned long long*)alloc(512ull << 10); // [4][1024][16] u64
  short* Qbf   = (short*)alloc(8ull << 20);
  short* Kbf   = (short*)alloc(8ull << 20);   // reused as AttnO
  short* Wt3   = (short*)alloc(6ull << 20);   // Wq^T | Wk^T | Wp^T bf16
  short* Qproj = (short*)alloc(8ull << 20);
  short* Kproj = (short*)alloc(8ull << 20);
  short* Vtg   = (short*)alloc(8ull << 20);
  short* AttnO = Kbf;

  k_pack_mask<<<2048, 256, 0, stream>>>((const unsigned*)mask_raw, packb, 4 * 1024 * 1024);
  k_cvt_bf16<<<dim3(1024, 2), 256, 0, stream>>>(query, Qbf, key_in, Kbf,
                                                (4 * 1024 * 1024) / 4);
  k_transpose_cvt<<<dim3(32, 32, 3), dim3(32, 8), 0, stream>>>(Wq, Wk, Wp, Wt3);

  dim3 gqk(8, 32, 2);  // N/128, M/128, {Q,K}
  k_gemm_qk<<<gqk, 256, 0, stream>>>(Qbf, Kbf, Wt3, bq, bk, Qproj, Kproj);

  k_vt_transpose<<<dim3(16, 16, 4), 256, 0, stream>>>(Qproj, Vtg);
  k_attention<<<512, 512, 0, stream>>>(Qproj, Kproj, Vtg, packb, AttnO);

  k_gemm_out<<<dim3(8, 32), 256, 0, stream>>>(AttnO, Wt3 + 2 * 1024 * 1024, bp,
                                              (float*)d_out);
}

// Round 9
// 105.144 us; speedup vs baseline: 1.0206x; 1.0206x over previous
//
#include <hip/hip_runtime.h>
#include <hip/hip_bf16.h>

using bf16x8 = __attribute__((ext_vector_type(8))) short;
using f32x4  = __attribute__((ext_vector_type(4))) float;

static __device__ __forceinline__ short f2bf(float f) {
  union { float f; unsigned u; } x; x.f = f;
  unsigned r = x.u + 0x7fffu + ((x.u >> 16) & 1u);
  return (short)(r >> 16);
}
static __device__ __forceinline__ float bf2f(short b) {
  union { unsigned u; float f; } x; x.u = ((unsigned)(unsigned short)b) << 16;
  return x.f;
}
static __device__ __forceinline__ unsigned pack_bf2(float lo, float hi) {
  __hip_bfloat162 h = __float22bfloat162_rn(float2{lo, hi});   // v_cvt_pk_bf16_f32
  unsigned u; __builtin_memcpy(&u, &h, 4); return u;
}
static __device__ __forceinline__ float exp2_raw(float x) {
  float r; asm("v_exp_f32 %0, %1" : "=v"(r) : "v"(x)); return r;  // 1 inst, no libm fixups
}
static __device__ __forceinline__ void gll16(const void* g, void* l) {
  __builtin_amdgcn_global_load_lds((__attribute__((address_space(1))) const void*)g,
                                   (__attribute__((address_space(3))) void*)l, 16, 0, 0);
}

// ---------------- mask -> bit-packed u64 per (row, 64-key tile) ----------------
__global__ void k_pack_mask(const unsigned* __restrict__ src_u32,
                            unsigned long long* __restrict__ out, int n) {
  unsigned probe = src_u32[threadIdx.x & 63];
  const bool u8mode = (__ballot(probe > 1u) != 0ull);   // block-uniform
  const unsigned char* s8 = (const unsigned char*)src_u32;
  const int* s32 = (const int*)src_u32;
  for (int e = blockIdx.x * blockDim.x + threadIdx.x; e < n; e += gridDim.x * blockDim.x) {
    int v = u8mode ? (int)s8[e] : s32[e];
    unsigned long long b = __ballot(v != 0);
    if ((threadIdx.x & 63) == 0) out[e >> 6] = b;
  }
}

// ---------------- f32 -> bf16 (two tensors, y-fused) ----------------
__global__ void k_cvt_bf16(const float* __restrict__ in0, short* __restrict__ out0,
                           const float* __restrict__ in1, short* __restrict__ out1, int n4) {
  const float* in = blockIdx.y ? in1 : in0;
  short* out = blockIdx.y ? out1 : out0;
  for (int i = blockIdx.x * blockDim.x + threadIdx.x; i < n4; i += gridDim.x * blockDim.x) {
    float4 v = reinterpret_cast<const float4*>(in)[i];
    short4 o;
    o.x = f2bf(v.x); o.y = f2bf(v.y); o.z = f2bf(v.z); o.w = f2bf(v.w);
    reinterpret_cast<short4*>(out)[i] = o;
  }
}

// transpose 1024x1024 f32 W[k][n] -> bf16 Wt[n][k]; z selects one of 3 weights
__global__ void k_transpose_cvt(const float* __restrict__ W0, const float* __restrict__ W1,
                                const float* __restrict__ W2, short* __restrict__ out3) {
  __shared__ float tile[32][33];
  const float* in = blockIdx.z == 0 ? W0 : (blockIdx.z == 1 ? W1 : W2);
  short* out = out3 + (size_t)blockIdx.z * 1024 * 1024;
  int x = blockIdx.x * 32 + threadIdx.x;
  int y0 = blockIdx.y * 32;
  for (int j = 0; j < 32; j += 8)
    tile[threadIdx.y + j][threadIdx.x] = in[(size_t)(y0 + threadIdx.y + j) * 1024 + x];
  __syncthreads();
  int xo = blockIdx.y * 32 + threadIdx.x;
  int yo = blockIdx.x * 32;
  for (int j = 0; j < 32; j += 8)
    out[(size_t)(yo + threadIdx.y + j) * 1024 + xo] = f2bf(tile[threadIdx.x][threadIdx.y + j]);
}

// transpose bf16 Qp[b, s, h*64+d] -> Vtg[(b*16+h)*64+d][s]  (per-head V^T)
__global__ void k_vt_transpose(const short* __restrict__ Qp, short* __restrict__ Vtg) {
  __shared__ short T[64 * 64];
  const int st = blockIdx.x, h = blockIdx.y, b = blockIdx.z;
  const int tid = threadIdx.x;
#pragma unroll
  for (int c = 0; c < 2; ++c) {
    int ch = c * 256 + tid;
    int row = ch >> 3, cn = ch & 7;
    bf16x8 v = *reinterpret_cast<const bf16x8*>(
        &Qp[(size_t)(b * 1024 + st * 64 + row) * 1024 + h * 64 + cn * 8]);
    *reinterpret_cast<bf16x8*>(&T[row * 64 + ((cn ^ (row & 7)) * 8)]) = v;
  }
  __syncthreads();
#pragma unroll
  for (int c = 0; c < 2; ++c) {
    int ch = c * 256 + tid;
    int d = ch >> 3, sc = ch & 7;
    bf16x8 v;
#pragma unroll
    for (int j = 0; j < 8; ++j) {
      int s_loc = sc * 8 + j;
      v[j] = T[s_loc * 64 + (((d >> 3) ^ j) * 8) + (d & 7)];
    }
    *reinterpret_cast<bf16x8*>(
        &Vtg[(size_t)((b * 16 + h) * 64 + d) * 1024 + st * 64 + sc * 8]) = v;
  }
}

// ---------------- bf16 MFMA GEMM body: C = A @ Bt^T + bias ----------------
// 128xBN tile, 4 waves (2x2), BK=64, 2-buffer, early-issue stage -> compute
// -> vmcnt(0)+barrier. Conflict-free chunk^row swizzle. BN=128 for 512-block
// z=2 launches (2 blk/CU exact); BN=64 for single GEMMs (512 blocks, 48KB LDS).
template<int OUT_BF16, int BN, int M, int N, int K>
__device__ __forceinline__ void gemm_body(const short* __restrict__ A,
                                          const short* __restrict__ Bt,
                                          const float* __restrict__ bias,
                                          void* __restrict__ C) {
  __shared__ short Al[2][128 * 64];
  __shared__ short Bl[2][BN * 64];
  constexpr int JF = BN / 32;        // N-frags per wave (wave covers BN/2 cols)
  const int tid  = threadIdx.x;
  const int lane = tid & 63, wid = tid >> 6;
  const int g = lane >> 4, lr = lane & 15;
  const int wm = wid >> 1, wn = wid & 1;
  constexpr int nbx = N / BN;
  constexpr int nwg = nbx * (M >> 7);
  const int lin = blockIdx.y * nbx + blockIdx.x;
  const int orig = (lin & 7) * (nwg >> 3) + (lin >> 3);   // XCD swizzle (nwg % 8 == 0)
  const int m0 = (orig / nbx) * 128, n0 = (orig % nbx) * BN;
  const int srow = lane >> 3;
  const int sch  = ((lane & 7) ^ srow) * 8;     // source chunk swizzle (row&7 == srow)

  f32x4 acc[4][JF];
#pragma unroll
  for (int i = 0; i < 4; ++i)
#pragma unroll
    for (int j = 0; j < JF; ++j) acc[i][j] = (f32x4){0.f, 0.f, 0.f, 0.f};

  constexpr int NT = K >> 6;
  auto stage = [&](int buf, int kt) {
#pragma unroll
    for (int s = 0; s < 4; ++s)
      gll16(&A[(size_t)(m0 + s * 32 + wid * 8 + srow) * K + kt + sch],
            &Al[buf][(s * 32 + wid * 8) * 64]);
#pragma unroll
    for (int s = 0; s < BN / 32; ++s)
      gll16(&Bt[(size_t)(n0 + s * 32 + wid * 8 + srow) * K + kt + sch],
            &Bl[buf][(s * 32 + wid * 8) * 64]);
  };

  stage(0, 0);
  asm volatile("s_waitcnt vmcnt(0)" ::: "memory");
  __builtin_amdgcn_s_barrier();
  asm volatile("" ::: "memory");

#pragma unroll 1
  for (int t = 0; t < NT; ++t) {
    const int cur = t & 1;
    if (t + 1 < NT) stage(cur ^ 1, (t + 1) * 64);   // readers of that buf done last iter
#pragma unroll
    for (int kb = 0; kb < 2; ++kb) {
      const int cs = ((kb * 4 + g) ^ (lr & 7)) * 8;      // swizzled read chunk
      bf16x8 af[4], bfr[JF];
#pragma unroll
      for (int i = 0; i < 4; ++i)
        af[i] = *reinterpret_cast<const bf16x8*>(&Al[cur][(wm * 64 + i * 16 + lr) * 64 + cs]);
#pragma unroll
      for (int j = 0; j < JF; ++j)
        bfr[j] = *reinterpret_cast<const bf16x8*>(
            &Bl[cur][(wn * (BN / 2) + j * 16 + lr) * 64 + cs]);
#pragma unroll
      for (int i = 0; i < 4; ++i)
#pragma unroll
        for (int j = 0; j < JF; ++j)
          acc[i][j] = __builtin_amdgcn_mfma_f32_16x16x32_bf16(af[i], bfr[j], acc[i][j], 0, 0, 0);
    }
    if (t + 1 < NT) {
      asm volatile("s_waitcnt vmcnt(0)" ::: "memory");  // stage(t+1) complete (had full flight)
      __builtin_amdgcn_s_barrier();                     // + everyone done reading cur
      asm volatile("" ::: "memory");
    }
  }

#pragma unroll
  for (int i = 0; i < 4; ++i) {
    int row = m0 + wm * 64 + i * 16 + g * 4;
#pragma unroll
    for (int j = 0; j < JF; ++j) {
      int col = n0 + wn * (BN / 2) + j * 16 + lr;
      float bv = bias[col];
#pragma unroll
      for (int r = 0; r < 4; ++r) {
        float v = acc[i][j][r] + bv;
        if (OUT_BF16) ((short*)C)[(size_t)(row + r) * N + col] = f2bf(v);
        else          ((float*)C)[(size_t)(row + r) * N + col] = v;
      }
    }
  }
}

// z=0: Q projection, z=1: K projection (128x128, 512 blocks total = 2/CU)
__launch_bounds__(256)
__global__ void k_gemm_qk(const short* __restrict__ A0, const short* __restrict__ A1,
                          const short* __restrict__ Bt3,
                          const float* __restrict__ b0, const float* __restrict__ b1,
                          short* __restrict__ C0, short* __restrict__ C1) {
  if (blockIdx.z == 0) gemm_body<1, 128, 4096, 1024, 1024>(A0, Bt3,               b0, C0);
  else                 gemm_body<1, 128, 4096, 1024, 1024>(A1, Bt3 + 1024 * 1024, b1, C1);
}

// single GEMM: 128x64 tile -> 512 blocks (2/CU); 48KB LDS
__launch_bounds__(256)
__global__ void k_gemm_out(const short* __restrict__ A, const short* __restrict__ Bt,
                           const float* __restrict__ bias, float* __restrict__ C) {
  gemm_body<0, 64, 4096, 1024, 1024>(A, Bt, bias, C);
}

// ---------------- fused masked attention, swapped-operand flash ----------------
// Same structure as R7/R8; P staging re-laid-out as XOR-chunk-swizzled [16][64]
// (was pad-72: 8-way bank conflict on the pa b128 reads; now 2-way = free).
__launch_bounds__(512)
__global__ void k_attention(const short* __restrict__ Qp, const short* __restrict__ Kp,
                            const short* __restrict__ Vtg,
                            const unsigned long long* __restrict__ mb,
                            short* __restrict__ O) {
  __shared__ short Kl[3][64 * 64];   // [key][d], chunk-swizzled linear
  __shared__ short Vl[3][64 * 64];   // [d][key], chunk-swizzled linear
  __shared__ short Pl[8][16 * 64];   // per-wave P[q][key], chunk ^ (q&7) swizzle
  const int tid  = threadIdx.x;
  const int lane = tid & 63, wid = tid >> 6;
  const int g = lane >> 4, lr = lane & 15;
  const int g4 = 4 * g;
  const int bid = (blockIdx.x & 7) * 64 + (blockIdx.x >> 3);  // XCD swizzle
  const int qt = bid & 7, h = (bid >> 3) & 15, b = bid >> 7;
  const int qb = qt * 128 + wid * 16;
  const int srow = lane >> 3;
  const int sch  = ((lane & 7) ^ srow) * 8;

  const size_t qrow = (size_t)(b * 1024 + qb + lr);
  const float qs = 0.125f * 1.44269504088896340736f;
  bf16x8 aq[2];
#pragma unroll
  for (int db = 0; db < 2; ++db) {
    bf16x8 raw = *reinterpret_cast<const bf16x8*>(&Qp[qrow * 1024 + h * 64 + db * 32 + g * 8]);
#pragma unroll
    for (int j = 0; j < 8; j += 2) {
      unsigned pk = pack_bf2(bf2f(raw[j]) * qs, bf2f(raw[j + 1]) * qs);
      aq[db][j]     = (short)(pk & 0xffffu);
      aq[db][j + 1] = (short)(pk >> 16);
    }
  }

  const unsigned long long* mrow = &mb[qrow * 16];
  const short* Ksrc = &Kp[(size_t)(b * 1024 + wid * 8 + srow) * 1024 + h * 64 + sch];
  const short* Vsrc = &Vtg[(size_t)((b * 16 + h) * 64 + wid * 8 + srow) * 1024 + sch];

  f32x4 o[4];
#pragma unroll
  for (int d = 0; d < 4; ++d) o[d] = (f32x4){0.f, 0.f, 0.f, 0.f};
  float l_part = 0.f;
  short* Prow = &Pl[wid][lr * 64];   // this wave's q-row (lr) base

  gll16(Ksrc,                     &Kl[0][(wid * 8) * 64]);
  gll16(Vsrc,                     &Vl[0][(wid * 8) * 64]);
  gll16(Ksrc + (size_t)64 * 1024, &Kl[1][(wid * 8) * 64]);
  gll16(Vsrc + 64,                &Vl[1][(wid * 8) * 64]);
  unsigned long long mwA = mrow[0];
  unsigned long long mwB = mrow[1];
  unsigned long long mwC = 0;
  const float keep = (mwA & 1ull) ? 0.f : 1.f;   // redundant row-keep, ~mask[b,q,0]

  int cur = 0;   // kt % 3
  int b2  = 2;   // (kt+2) % 3 == (kt-1) % 3
#pragma unroll 1
  for (int kt = 0; kt < 16; ++kt) {
    if (kt >= 1) {
      const short* Vb = Vl[b2];
      __builtin_amdgcn_s_setprio(1);
#pragma unroll
      for (int kb = 0; kb < 2; ++kb) {
        bf16x8 pa = *reinterpret_cast<const bf16x8*>(
            &Prow[(((kb * 4 + g) ^ (lr & 7)) * 8)]);          // swizzled P read (2-way)
        const int cs = ((kb * 4 + g) ^ (lr & 7)) * 8;
#pragma unroll
        for (int d = 0; d < 4; ++d) {
          bf16x8 vf = *reinterpret_cast<const bf16x8*>(&Vb[(d * 16 + lr) * 64 + cs]);
          o[d] = __builtin_amdgcn_mfma_f32_16x16x32_bf16(vf, pa, o[d], 0, 0, 0);
        }
      }
      __builtin_amdgcn_s_setprio(0);
    }

    if (kt < 15) asm volatile("s_waitcnt vmcnt(4)" ::: "memory");  // stage(kt) drained
    else         asm volatile("s_waitcnt vmcnt(0)" ::: "memory");
    __builtin_amdgcn_s_barrier();
    asm volatile("" ::: "memory");

    if (kt + 2 < 16) {
      gll16(Ksrc + (size_t)(kt + 2) * 64 * 1024, &Kl[b2][(wid * 8) * 64]);
      gll16(Vsrc + (kt + 2) * 64,                &Vl[b2][(wid * 8) * 64]);
      mwC = mrow[kt + 2];                        // consumed 2 iters later
    }

    const unsigned mlo = (unsigned)mwA;
    const unsigned mhi = (unsigned)(mwA >> 32);

#pragma unroll
    for (int kc = 0; kc < 4; ++kc) {
      f32x4 a = (f32x4){0.f, 0.f, 0.f, 0.f};
      __builtin_amdgcn_s_setprio(1);
#pragma unroll
      for (int db = 0; db < 2; ++db) {
        bf16x8 kf = *reinterpret_cast<const bf16x8*>(
            &Kl[cur][(kc * 16 + lr) * 64 + (((db * 4 + g) ^ (lr & 7)) * 8)]);
        a = __builtin_amdgcn_mfma_f32_16x16x32_bf16(kf, aq[db], a, 0, 0, 0);
      }
      __builtin_amdgcn_s_setprio(0);
      const unsigned wk = ((kc < 2 ? mlo : mhi) >> (((kc & 1) << 4) + g4)) & 0xFu;
      float p0 = (wk & 1u) ? 0.f : exp2_raw(a[0]);
      float p1 = (wk & 2u) ? 0.f : exp2_raw(a[1]);
      float p2 = (wk & 4u) ? 0.f : exp2_raw(a[2]);
      float p3 = (wk & 8u) ? 0.f : exp2_raw(a[3]);
      l_part += (p0 + p1) + (p2 + p3);
      unsigned lo = pack_bf2(p0, p1), hi = pack_bf2(p2, p3);
      unsigned long long w = (unsigned long long)lo | ((unsigned long long)hi << 32);
      // keys kc*16+4g..+3 live at chunk 2kc+(g>>1), byte (g&1)*8; chunk ^= lr&7
      *reinterpret_cast<unsigned long long*>(
          &Prow[((2 * kc + (g >> 1)) ^ (lr & 7)) * 8 + (g & 1) * 4]) = w;
    }
    mwA = mwB; mwB = mwC;
    cur = (cur == 2) ? 0 : cur + 1;
    b2  = (b2  == 2) ? 0 : b2  + 1;
    asm volatile("" ::: "memory");
  }

  {  // final PV(15): V buf 15%3 == 0 (staged at kt=13, never overwritten)
    const short* Vb = Vl[0];
    __builtin_amdgcn_s_setprio(1);
#pragma unroll
    for (int kb = 0; kb < 2; ++kb) {
      bf16x8 pa = *reinterpret_cast<const bf16x8*>(
          &Prow[(((kb * 4 + g) ^ (lr & 7)) * 8)]);
      const int cs = ((kb * 4 + g) ^ (lr & 7)) * 8;
#pragma unroll
      for (int d = 0; d < 4; ++d) {
        bf16x8 vf = *reinterpret_cast<const bf16x8*>(&Vb[(d * 16 + lr) * 64 + cs]);
        o[d] = __builtin_amdgcn_mfma_f32_16x16x32_bf16(vf, pa, o[d], 0, 0, 0);
      }
    }
    __builtin_amdgcn_s_setprio(0);
  }

  float l_run = l_part;
  l_run += __shfl_xor(l_run, 16);
  l_run += __shfl_xor(l_run, 32);

  // epilogue: normalize + row-keep; stage O^T rows (d-major) into Pl, swizzled
  const float inv = (l_run > 0.f) ? keep / l_run : 0.f;
#pragma unroll
  for (int d = 0; d < 4; ++d) {
    unsigned lo = pack_bf2(o[d][0] * inv, o[d][1] * inv);
    unsigned hi = pack_bf2(o[d][2] * inv, o[d][3] * inv);
    unsigned long long w = (unsigned long long)lo | ((unsigned long long)hi << 32);
    // dglobal d*16+4g..+3 -> chunk 2d+(g>>1), byte (g&1)*8; chunk ^= lr&7
    *reinterpret_cast<unsigned long long*>(
        &Prow[((2 * d + (g >> 1)) ^ (lr & 7)) * 8 + (g & 1) * 4]) = w;
  }
#pragma unroll
  for (int it = 0; it < 2; ++it) {
    int qq = it * 8 + srow;
    bf16x8 val = *reinterpret_cast<const bf16x8*>(
        &Pl[wid][qq * 64 + (((lane & 7) ^ (qq & 7)) * 8)]);   // orig chunk = lane&7
    *reinterpret_cast<bf16x8*>(
        &O[(size_t)(b * 1024 + qt * 128 + wid * 16 + qq) * 1024 + h * 64 + (lane & 7) * 8]) = val;
  }
}

extern "C" void kernel_launch(void* const* d_in, const int* in_sizes, int n_in,
                              void* d_out, int out_size, void* d_ws, size_t ws_size,
                              hipStream_t stream) {
  const float* query  = (const float*)d_in[0];
  const float* key_in = (const float*)d_in[1];
  const void*  mask_raw = d_in[2];
  const float* Wq = (const float*)d_in[3];
  const float* bq = (const float*)d_in[4];
  const float* Wk = (const float*)d_in[5];
  const float* bk = (const float*)d_in[6];
  const float* Wp = (const float*)d_in[7];
  const float* bp = (const float*)d_in[8];

  char* ws = (char*)d_ws;
  size_t off = 0;
  auto alloc = [&](size_t bytes) {
    char* p = ws + off;
    off = (off + bytes + 255) & ~(size_t)255;
    return p;
  };
  unsigned long long* packb = (unsigned long long*)alloc(512ull << 10); // [4][1024][16] u64
  short* Qbf   = (short*)alloc(8ull << 20);
  short* Kbf   = (short*)alloc(8ull << 20);   // reused as AttnO
  short* Wt3   = (short*)alloc(6ull << 20);   // Wq^T | Wk^T | Wp^T bf16
  short* Qproj = (short*)alloc(8ull << 20);
  short* Kproj = (short*)alloc(8ull << 20);
  short* Vtg   = (short*)alloc(8ull << 20);
  short* AttnO = Kbf;

  k_pack_mask<<<2048, 256, 0, stream>>>((const unsigned*)mask_raw, packb, 4 * 1024 * 1024);
  k_cvt_bf16<<<dim3(1024, 2), 256, 0, stream>>>(query, Qbf, key_in, Kbf,
                                                (4 * 1024 * 1024) / 4);
  k_transpose_cvt<<<dim3(32, 32, 3), dim3(32, 8), 0, stream>>>(Wq, Wk, Wp, Wt3);

  dim3 gqk(8, 32, 2);  // N/128, M/128, {Q,K}
  k_gemm_qk<<<gqk, 256, 0, stream>>>(Qbf, Kbf, Wt3, bq, bk, Qproj, Kproj);

  k_vt_transpose<<<dim3(16, 16, 4), 256, 0, stream>>>(Qproj, Vtg);
  k_attention<<<512, 512, 0, stream>>>(Qproj, Kproj, Vtg, packb, AttnO);

  k_gemm_out<<<dim3(16, 32), 256, 0, stream>>>(AttnO, Wt3 + 2 * 1024 * 1024, bp,
                                               (float*)d_out);
}